// Round 10
// baseline (133.917 us; speedup 1.0000x reference)
//
#include <hip/hip_runtime.h>
#include <cmath>

// MHSA cosine-attention block, MI355X/gfx950.  Round 10.
// K1: QKV projection as MFMA GEMM (R8/R9). Q pre-scaled by log2e.
// K2: flash attention v6: BARRIER-FREE. No LDS K staging -- K fragments
//     register ping-ponged one 64-key chunk ahead (kA/kB rotate); S in 2
//     key-tile pairs (bounds live VGPRs under the (256,4) cap); V loaded
//     under the exp chain; P same-wave LDS round trip. Zero __syncthreads.
// K3: vectorized partial reduce -- b128 bf16x8 numPb loads, contiguous
//     1 KB/wave per instr; two ks-half partials merged via LDS.

typedef __bf16 bf16x8 __attribute__((ext_vector_type(8)));
typedef __bf16 bf16x4 __attribute__((ext_vector_type(4)));
typedef float f4_t __attribute__((ext_vector_type(4)));

#define LQ 4096       // sequence length H*W
#define NH 4          // n*heads
#define KS 8          // key splits

__device__ inline f4_t mfma16(bf16x8 a, bf16x8 b, f4_t c) {
    return __builtin_amdgcn_mfma_f32_16x16x32_bf16(a, b, c, 0, 0, 0);
}

__device__ inline bf16x8 cvt8(const float* p) {
    f4_t a = *(const f4_t*)p, b = *(const f4_t*)(p + 4);
    bf16x8 r;
    r[0] = (__bf16)a[0]; r[1] = (__bf16)a[1]; r[2] = (__bf16)a[2]; r[3] = (__bf16)a[3];
    r[4] = (__bf16)b[0]; r[5] = (__bf16)b[1]; r[6] = (__bf16)b[2]; r[7] = (__bf16)b[3];
    return r;
}

// ---------------------------------------------------------------------------
// Kernel 1: QKV projection + normalize via MFMA.  (unchanged from R9)
// grid: dim3(128, 2) = l-tile(32) x n.  block: 256 thr = 4 waves.
// ---------------------------------------------------------------------------
__global__ __launch_bounds__(256) void k1_qkv(
        const float* __restrict__ x,
        const float* __restrict__ Wq, const float* __restrict__ bq,
        const float* __restrict__ Wk, const float* __restrict__ bk,
        const float* __restrict__ Wv, const float* __restrict__ bv,
        __bf16* __restrict__ Qb, __bf16* __restrict__ Kb,
        __bf16* __restrict__ Vtb) {
    const int tid  = threadIdx.x;
    const int lane = tid & 63;
    const int w    = tid >> 6;
    const int quad = lane >> 4;
    const int l15  = lane & 15;
    const int lt   = blockIdx.x;
    const int n    = blockIdx.y;
    const int l0   = lt * 32;

    __shared__ __bf16 xl[32][72];   // [l][c] bf16, pitch 72

    {
        const int c0 = tid >> 5, l = tid & 31;
#pragma unroll
        for (int i = 0; i < 8; ++i) {
            const int c = c0 + i * 8;
            xl[l][c] = (__bf16)x[((size_t)n * 64 + c) * LQ + l0 + l];
        }
    }

    const float* Wqk = (w < 2) ? Wq : Wk;
    const float* bqk = (w < 2) ? bq : bk;
    const int h = w & 1;

    bf16x8 af[4][2], av[2];
#pragma unroll
    for (int t = 0; t < 4; ++t)
#pragma unroll
        for (int kh = 0; kh < 2; ++kh)
            af[t][kh] = cvt8(Wqk + (size_t)(h * 64 + t * 16 + l15) * 64
                                  + kh * 32 + quad * 8);
#pragma unroll
    for (int kh = 0; kh < 2; ++kh)
        av[kh] = cvt8(Wv + (size_t)(w * 16 + l15) * 64 + kh * 32 + quad * 8);

    f4_t binit[4], bvinit;
#pragma unroll
    for (int t = 0; t < 4; ++t)
#pragma unroll
        for (int r = 0; r < 4; ++r)
            binit[t][r] = bqk[h * 64 + t * 16 + quad * 4 + r];
#pragma unroll
    for (int r = 0; r < 4; ++r)
        bvinit[r] = bv[w * 16 + quad * 4 + r];

    __syncthreads();

    f4_t acc[4][2], vacc[2];
#pragma unroll
    for (int lsub = 0; lsub < 2; ++lsub) {
        bf16x8 bf0 = *(const bf16x8*)&xl[lsub * 16 + l15][quad * 8];
        bf16x8 bf1 = *(const bf16x8*)&xl[lsub * 16 + l15][32 + quad * 8];
#pragma unroll
        for (int t = 0; t < 4; ++t) {
            f4_t a = mfma16(af[t][0], bf0, binit[t]);
            acc[t][lsub] = mfma16(af[t][1], bf1, a);
        }
        f4_t va = mfma16(av[0], bf0, bvinit);
        vacc[lsub] = mfma16(av[1], bf1, va);
    }

    const int nh = n * 2 + h;
    __bf16* dst  = (w < 2) ? Qb : Kb;
    const float post = (w < 2) ? 1.44269504f : 1.0f;
#pragma unroll
    for (int lsub = 0; lsub < 2; ++lsub) {
        float ss = 0.f;
#pragma unroll
        for (int t = 0; t < 4; ++t)
#pragma unroll
            for (int r = 0; r < 4; ++r)
                ss = fmaf(acc[t][lsub][r], acc[t][lsub][r], ss);
        ss += __shfl_xor(ss, 16, 64);
        ss += __shfl_xor(ss, 32, 64);
        const float rn = post / fmaxf(sqrtf(ss), 1e-6f);

        const int l = l0 + lsub * 16 + l15;
#pragma unroll
        for (int t = 0; t < 4; ++t) {
            bf16x4 pk;
#pragma unroll
            for (int r = 0; r < 4; ++r) pk[r] = (__bf16)(acc[t][lsub][r] * rn);
            const int kc = t * 2 + (quad >> 1);
            *(bf16x4*)(dst + ((size_t)(nh * 8 + kc) * LQ + l) * 8 + (quad & 1) * 4) = pk;
        }
#pragma unroll
        for (int r = 0; r < 4; ++r) {
            const int vrow = w * 16 + quad * 4 + r;
            Vtb[(size_t)(n * 64 + vrow) * LQ + l] = (__bf16)vacc[lsub][r];
        }
    }
}

// ---------------------------------------------------------------------------
// Kernel 2: flash attention v6 -- barrier-free, register-pipelined K.
// grid: (32 q-blocks of 128, nh=4, ks=8) = 1024 blocks x 4 waves (4/CU).
// 8 chunks x 64 keys; K frags for chunk ch+1 prefetched into registers
// while chunk ch computes.  Zero __syncthreads.
// ---------------------------------------------------------------------------
__global__ __launch_bounds__(256, 4) void k2_attn(
        const __bf16* __restrict__ Qb, const __bf16* __restrict__ Kb,
        const __bf16* __restrict__ Vtb,
        __bf16* __restrict__ numPb, float* __restrict__ denP) {
    const int tid  = threadIdx.x;
    const int lane = tid & 63;
    const int wave = tid >> 6;
    const int quad = lane >> 4;
    const int l15  = lane & 15;
    const int nh   = blockIdx.y;
    const int ks   = blockIdx.z;
    const int qbase = blockIdx.x * 128 + wave * 32;
    const int kbase = ks * 512;

    __shared__ __bf16 P[4][2][16][72];   // [wave][qt][q-row][64 keys + pad]

    const f4_t fzero = {0.f, 0.f, 0.f, 0.f};

    // Q fragments (k8-tiled layout), reused for all 512 keys
    bf16x8 qf[2][2];
#pragma unroll
    for (int qt = 0; qt < 2; ++qt)
#pragma unroll
        for (int kh = 0; kh < 2; ++kh)
            qf[qt][kh] = *(const bf16x8*)(Qb +
                ((size_t)(nh * 8 + kh * 4 + quad) * LQ + qbase + qt * 16 + l15) * 8);

    f4_t racc[2][2];                     // [vt][qt]
#pragma unroll
    for (int a = 0; a < 2; ++a)
#pragma unroll
        for (int b = 0; b < 2; ++b) racc[a][b] = fzero;
    float den[2] = {0.f, 0.f};

    // K frag (kt, kh) of chunk ch lives at:
    //   Kb[((nh*8 + kh*4 + quad)*LQ + kbase + ch*64 + kt*16 + l15)*8]
    const __bf16* k_src0 = Kb + ((size_t)(nh * 8 + quad) * LQ + kbase + l15) * 8;
    const __bf16* k_src1 = Kb + ((size_t)(nh * 8 + 4 + quad) * LQ + kbase + l15) * 8;
    // V frag (vt, kp) of chunk ch: v_src + vt*16*LQ + ch*64 + kp*32
    const __bf16* v_src = Vtb + (size_t)(nh * 32 + l15) * LQ + kbase + quad * 8;

    bf16x8 kA[4][2], kB[4][2];
    // preload chunk 0 into kA
#pragma unroll
    for (int kt = 0; kt < 4; ++kt) {
        kA[kt][0] = *(const bf16x8*)(k_src0 + (size_t)(kt * 16) * 8);
        kA[kt][1] = *(const bf16x8*)(k_src1 + (size_t)(kt * 16) * 8);
    }

    auto step = [&](int ch, bf16x8 (&cur)[4][2], bf16x8 (&nxt)[4][2]) {
        // prefetch next chunk's K into the other register set
        if (ch < 7) {
#pragma unroll
            for (int kt = 0; kt < 4; ++kt) {
                nxt[kt][0] = *(const bf16x8*)(k_src0 +
                                (size_t)((ch + 1) * 64 + kt * 16) * 8);
                nxt[kt][1] = *(const bf16x8*)(k_src1 +
                                (size_t)((ch + 1) * 64 + kt * 16) * 8);
            }
        }

        bf16x8 vf[2][2];
        // S + exp in 2 key-tile pairs (bounds live registers)
#pragma unroll
        for (int pair = 0; pair < 2; ++pair) {
            f4_t s[2][2];
#pragma unroll
            for (int qt = 0; qt < 2; ++qt)
#pragma unroll
                for (int i = 0; i < 2; ++i) {
                    const int kt = pair * 2 + i;
                    f4_t t = mfma16(cur[kt][0], qf[qt][0], fzero);
                    s[qt][i] = mfma16(cur[kt][1], qf[qt][1], t);
                }
            if (pair == 0) {
                // V loads issued here: latency hides under the exp chains
#pragma unroll
                for (int vt = 0; vt < 2; ++vt)
#pragma unroll
                    for (int kp = 0; kp < 2; ++kp)
                        vf[vt][kp] = *(const bf16x8*)(v_src +
                            (size_t)vt * 16 * LQ + ch * 64 + kp * 32);
            }
#pragma unroll
            for (int qt = 0; qt < 2; ++qt)
#pragma unroll
                for (int i = 0; i < 2; ++i) {
                    const int kt = pair * 2 + i;
                    bf16x4 pv;
                    float d = 0.f;
#pragma unroll
                    for (int r = 0; r < 4; ++r) {
                        float p = __builtin_exp2f(s[qt][i][r]);
                        d += p;
                        pv[r] = (__bf16)p;
                    }
                    den[qt] += d;
                    *(bf16x4*)&P[wave][qt][l15][kt * 16 + quad * 4] = pv;
                }
        }

        // PV: A = V rows, B = P rows (same-wave LDS round trip, in-order DS)
#pragma unroll
        for (int qt = 0; qt < 2; ++qt)
#pragma unroll
            for (int kp = 0; kp < 2; ++kp) {
                bf16x8 pf = *(const bf16x8*)&P[wave][qt][l15][kp * 32 + quad * 8];
                racc[0][qt] = mfma16(vf[0][kp], pf, racc[0][qt]);
                racc[1][qt] = mfma16(vf[1][kp], pf, racc[1][qt]);
            }
    };

    for (int ch = 0; ch < 8; ch += 2) {
        step(ch,     kA, kB);
        step(ch + 1, kB, kA);
    }

    // den: reduce quad partials (same q = l15 across quads)
#pragma unroll
    for (int qt = 0; qt < 2; ++qt) {
        den[qt] += __shfl_xor(den[qt], 16, 64);
        den[qt] += __shfl_xor(den[qt], 32, 64);
    }

    const size_t pb = (size_t)(nh * KS + ks) * LQ;
    // numPb layout [nh][ks][q][v32] bf16 -- v-contiguous for k3
#pragma unroll
    for (int vt = 0; vt < 2; ++vt)
#pragma unroll
        for (int qt = 0; qt < 2; ++qt) {
            bf16x4 pk;
#pragma unroll
            for (int r = 0; r < 4; ++r) pk[r] = (__bf16)racc[vt][qt][r];
            *(bf16x4*)(numPb + (pb + qbase + qt * 16 + l15) * 32
                             + vt * 16 + quad * 4) = pk;
        }

    if (lane < 16)
#pragma unroll
        for (int qt = 0; qt < 2; ++qt)
            denP[pb + qbase + qt * 16 + lane] = den[qt];
}

// ---------------------------------------------------------------------------
// Kernel 3: vectorized bf16 partial reduce -> R, fp32 projection + residual.
// grid: dim3(256, 2) = l-tile(16) x n = 512 blocks.  block: 256 thr.
// Reduce map: tid = sh(1)|hh(1)|l(4)|vg(2) -> each thread 4x b128 loads,
// per-wave address span contiguous 1 KB per instruction.
// ---------------------------------------------------------------------------
__global__ __launch_bounds__(256) void k3_out(
        const __bf16* __restrict__ numPb, const float* __restrict__ denP,
        const float* __restrict__ Wm, const float* __restrict__ bm,
        const float* __restrict__ x, float* __restrict__ out) {
    const int tid = threadIdx.x;
    const int lt  = blockIdx.x;
    const int n   = blockIdx.y;
    const int l0  = lt * 16;

    __shared__ float Rps[2][64][17];   // [ks-half][j = h*32+v][l]
    __shared__ float dinv[2][16];

    if (tid < 32) {
        const int hh = tid >> 4, li = tid & 15;
        float s = 0.f;
#pragma unroll
        for (int k = 0; k < KS; ++k)
            s += denP[(size_t)((n * 2 + hh) * KS + k) * LQ + l0 + li];
        dinv[hh][li] = 1.0f / s;
    }

    // vectorized reduce over ks (two halves in parallel)
    {
        const int vg = tid & 3, l = (tid >> 2) & 15;
        const int hh = (tid >> 6) & 1, sh = tid >> 7;
        const size_t base = (size_t)(n * 2 + hh) * KS * LQ;
        float a[8] = {0.f, 0.f, 0.f, 0.f, 0.f, 0.f, 0.f, 0.f};
#pragma unroll
        for (int k = 0; k < 4; ++k) {
            const int kk = sh * 4 + k;
            bf16x8 v8 = *(const bf16x8*)(numPb +
                (base + (size_t)kk * LQ + l0 + l) * 32 + vg * 8);
#pragma unroll
            for (int j = 0; j < 8; ++j) a[j] += (float)v8[j];
        }
#pragma unroll
        for (int j = 0; j < 8; ++j)
            Rps[sh][hh * 32 + vg * 8 + j][l] = a[j];
    }
    __syncthreads();

    // projection: thread (l = tid&15, og = tid>>4) -> outputs og*4..+3
    const int l = tid & 15, og = tid >> 4;
    const float d0 = dinv[0][l], d1 = dinv[1][l];
    float rj[64];
#pragma unroll
    for (int j = 0; j < 64; ++j)
        rj[j] = (Rps[0][j][l] + Rps[1][j][l]) * (j < 32 ? d0 : d1);

#pragma unroll
    for (int oi = 0; oi < 4; ++oi) {
        const int o = og * 4 + oi;
        const float* wr = Wm + (size_t)o * 64;
        float a = bm[o];
#pragma unroll
        for (int j4 = 0; j4 < 16; ++j4) {
            f4_t t = *(const f4_t*)(wr + j4 * 4);
            a = fmaf(t[0], rj[j4 * 4 + 0], a);
            a = fmaf(t[1], rj[j4 * 4 + 1], a);
            a = fmaf(t[2], rj[j4 * 4 + 2], a);
            a = fmaf(t[3], rj[j4 * 4 + 3], a);
        }
        const size_t idx = (size_t)(n * 64 + o) * LQ + l0 + l;
        out[idx] = a + x[idx];
    }
}

// ---------------------------------------------------------------------------
extern "C" void kernel_launch(void* const* d_in, const int* in_sizes, int n_in,
                              void* d_out, int out_size, void* d_ws, size_t ws_size,
                              hipStream_t stream) {
    const float* x  = (const float*)d_in[0];
    const float* Wq = (const float*)d_in[1];
    const float* bq = (const float*)d_in[2];
    const float* Wk = (const float*)d_in[3];
    const float* bk = (const float*)d_in[4];
    const float* Wv = (const float*)d_in[5];
    const float* bv = (const float*)d_in[6];
    const float* Wm = (const float*)d_in[7];
    const float* bm = (const float*)d_in[8];
    float* out = (float*)d_out;

    // workspace carve: Qb 2MB | Kb 2MB | Vtb 1MB | numPb 8.4MB | denP 0.5MB
    __bf16* Qb    = (__bf16*)d_ws;
    __bf16* Kb    = Qb + (size_t)NH * LQ * 64;
    __bf16* Vtb   = Kb + (size_t)NH * LQ * 64;
    __bf16* numPb = Vtb + (size_t)NH * 32 * LQ;
    float*  denP  = (float*)(numPb + (size_t)NH * KS * LQ * 32);

    k1_qkv<<<dim3(128, 2), dim3(256), 0, stream>>>(x, Wq, bq, Wk, bk, Wv, bv,
                                                   Qb, Kb, Vtb);
    k2_attn<<<dim3(32, NH, KS), dim3(256), 0, stream>>>(Qb, Kb, Vtb, numPb, denP);
    k3_out<<<dim3(256, 2), dim3(256), 0, stream>>>(numPb, denP, Wm, bm, x, out);
}

// Round 11
// 112.127 us; speedup vs baseline: 1.1943x; 1.1943x over previous
//
#include <hip/hip_runtime.h>
#include <cmath>

// MHSA cosine-attention block, MI355X/gfx950.  Round 11.
// K1: QKV projection as MFMA GEMM (R8/R9). Q pre-scaled by log2e.
// K2: REVERTED to R9 (proven): 8 chunks x 64 keys, K double-buffered in
//     LDS (shuffled conflict-free slot map), K-frags in 2 pairs, V loads
//     at chunk start, P same-wave LDS round trip, bf16 partials.
//     (R10's barrier-free register-K spilled: VGPR=64 + 78 MB scratch.)
// K3: R10's vectorized partial reduce -- b128 bf16x8 numPb loads,
//     contiguous 1 KB/wave per instr; ks-half partials merged via LDS.

typedef __bf16 bf16x8 __attribute__((ext_vector_type(8)));
typedef __bf16 bf16x4 __attribute__((ext_vector_type(4)));
typedef float f4_t __attribute__((ext_vector_type(4)));

#define LQ 4096       // sequence length H*W
#define NH 4          // n*heads
#define KS 8          // key splits

__device__ inline f4_t mfma16(bf16x8 a, bf16x8 b, f4_t c) {
    return __builtin_amdgcn_mfma_f32_16x16x32_bf16(a, b, c, 0, 0, 0);
}

__device__ inline bf16x8 cvt8(const float* p) {
    f4_t a = *(const f4_t*)p, b = *(const f4_t*)(p + 4);
    bf16x8 r;
    r[0] = (__bf16)a[0]; r[1] = (__bf16)a[1]; r[2] = (__bf16)a[2]; r[3] = (__bf16)a[3];
    r[4] = (__bf16)b[0]; r[5] = (__bf16)b[1]; r[6] = (__bf16)b[2]; r[7] = (__bf16)b[3];
    return r;
}

// ---------------------------------------------------------------------------
// Kernel 1: QKV projection + normalize via MFMA.
// grid: dim3(128, 2) = l-tile(32) x n.  block: 256 thr = 4 waves.
// ---------------------------------------------------------------------------
__global__ __launch_bounds__(256) void k1_qkv(
        const float* __restrict__ x,
        const float* __restrict__ Wq, const float* __restrict__ bq,
        const float* __restrict__ Wk, const float* __restrict__ bk,
        const float* __restrict__ Wv, const float* __restrict__ bv,
        __bf16* __restrict__ Qb, __bf16* __restrict__ Kb,
        __bf16* __restrict__ Vtb) {
    const int tid  = threadIdx.x;
    const int lane = tid & 63;
    const int w    = tid >> 6;
    const int quad = lane >> 4;
    const int l15  = lane & 15;
    const int lt   = blockIdx.x;
    const int n    = blockIdx.y;
    const int l0   = lt * 32;

    __shared__ __bf16 xl[32][72];   // [l][c] bf16, pitch 72

    {
        const int c0 = tid >> 5, l = tid & 31;
#pragma unroll
        for (int i = 0; i < 8; ++i) {
            const int c = c0 + i * 8;
            xl[l][c] = (__bf16)x[((size_t)n * 64 + c) * LQ + l0 + l];
        }
    }

    const float* Wqk = (w < 2) ? Wq : Wk;
    const float* bqk = (w < 2) ? bq : bk;
    const int h = w & 1;

    bf16x8 af[4][2], av[2];
#pragma unroll
    for (int t = 0; t < 4; ++t)
#pragma unroll
        for (int kh = 0; kh < 2; ++kh)
            af[t][kh] = cvt8(Wqk + (size_t)(h * 64 + t * 16 + l15) * 64
                                  + kh * 32 + quad * 8);
#pragma unroll
    for (int kh = 0; kh < 2; ++kh)
        av[kh] = cvt8(Wv + (size_t)(w * 16 + l15) * 64 + kh * 32 + quad * 8);

    f4_t binit[4], bvinit;
#pragma unroll
    for (int t = 0; t < 4; ++t)
#pragma unroll
        for (int r = 0; r < 4; ++r)
            binit[t][r] = bqk[h * 64 + t * 16 + quad * 4 + r];
#pragma unroll
    for (int r = 0; r < 4; ++r)
        bvinit[r] = bv[w * 16 + quad * 4 + r];

    __syncthreads();

    f4_t acc[4][2], vacc[2];
#pragma unroll
    for (int lsub = 0; lsub < 2; ++lsub) {
        bf16x8 bf0 = *(const bf16x8*)&xl[lsub * 16 + l15][quad * 8];
        bf16x8 bf1 = *(const bf16x8*)&xl[lsub * 16 + l15][32 + quad * 8];
#pragma unroll
        for (int t = 0; t < 4; ++t) {
            f4_t a = mfma16(af[t][0], bf0, binit[t]);
            acc[t][lsub] = mfma16(af[t][1], bf1, a);
        }
        f4_t va = mfma16(av[0], bf0, bvinit);
        vacc[lsub] = mfma16(av[1], bf1, va);
    }

    const int nh = n * 2 + h;
    __bf16* dst  = (w < 2) ? Qb : Kb;
    const float post = (w < 2) ? 1.44269504f : 1.0f;
#pragma unroll
    for (int lsub = 0; lsub < 2; ++lsub) {
        float ss = 0.f;
#pragma unroll
        for (int t = 0; t < 4; ++t)
#pragma unroll
            for (int r = 0; r < 4; ++r)
                ss = fmaf(acc[t][lsub][r], acc[t][lsub][r], ss);
        ss += __shfl_xor(ss, 16, 64);
        ss += __shfl_xor(ss, 32, 64);
        const float rn = post / fmaxf(sqrtf(ss), 1e-6f);

        const int l = l0 + lsub * 16 + l15;
#pragma unroll
        for (int t = 0; t < 4; ++t) {
            bf16x4 pk;
#pragma unroll
            for (int r = 0; r < 4; ++r) pk[r] = (__bf16)(acc[t][lsub][r] * rn);
            const int kc = t * 2 + (quad >> 1);
            *(bf16x4*)(dst + ((size_t)(nh * 8 + kc) * LQ + l) * 8 + (quad & 1) * 4) = pk;
        }
#pragma unroll
        for (int r = 0; r < 4; ++r) {
            const int vrow = w * 16 + quad * 4 + r;
            Vtb[(size_t)(n * 64 + vrow) * LQ + l] = (__bf16)vacc[lsub][r];
        }
    }
}

// ---------------------------------------------------------------------------
// Kernel 2: flash attention (R9 proven version).
// grid: (32 q-blocks of 128, nh=4, ks=8) = 1024 blocks x 4 waves.
// 8 chunks x 64 keys; K double-buffered in LDS (shuffled map: slot
// s <-> (kc = ((s>>6)&1)*4 + ((s>>4)&3), l = (s>>7)*16 + (s&15)));
// staging writes and frag reads both contiguous 1 KB/wave.
// ---------------------------------------------------------------------------
__global__ __launch_bounds__(256, 4) void k2_attn(
        const __bf16* __restrict__ Qb, const __bf16* __restrict__ Kb,
        const __bf16* __restrict__ Vtb,
        __bf16* __restrict__ numPb, float* __restrict__ denP) {
    const int tid  = threadIdx.x;
    const int lane = tid & 63;
    const int wave = tid >> 6;
    const int quad = lane >> 4;
    const int l15  = lane & 15;
    const int nh   = blockIdx.y;
    const int ks   = blockIdx.z;
    const int qbase = blockIdx.x * 128 + wave * 32;
    const int kbase = ks * 512;

    __shared__ __bf16 Kl[2][4096];       // 2 x 8 KB staged K chunks (64 keys)
    __shared__ __bf16 P[4][2][16][72];   // [wave][qt][q-row][64 keys + pad]

    const f4_t fzero = {0.f, 0.f, 0.f, 0.f};

    // staging: 2 slots per thread (s = tid, s = tid + 256)
    const __bf16* s_src0, * s_src1;
    {
        const int s0 = tid, s1 = tid + 256;
        const int kc0 = ((s0 >> 6) & 1) * 4 + ((s0 >> 4) & 3);
        const int ll0 = (s0 >> 7) * 16 + (s0 & 15);
        const int kc1 = ((s1 >> 6) & 1) * 4 + ((s1 >> 4) & 3);
        const int ll1 = (s1 >> 7) * 16 + (s1 & 15);
        s_src0 = Kb + ((size_t)(nh * 8 + kc0) * LQ + kbase + ll0) * 8;
        s_src1 = Kb + ((size_t)(nh * 8 + kc1) * LQ + kbase + ll1) * 8;
    }

    // Q fragments (k8-tiled layout), reused for all 512 keys
    bf16x8 qf[2][2];
#pragma unroll
    for (int qt = 0; qt < 2; ++qt)
#pragma unroll
        for (int kh = 0; kh < 2; ++kh)
            qf[qt][kh] = *(const bf16x8*)(Qb +
                ((size_t)(nh * 8 + kh * 4 + quad) * LQ + qbase + qt * 16 + l15) * 8);

    f4_t racc[2][2];                     // [vt][qt]
#pragma unroll
    for (int a = 0; a < 2; ++a)
#pragma unroll
        for (int b = 0; b < 2; ++b) racc[a][b] = fzero;
    float den[2] = {0.f, 0.f};

    // V base: lane reads V[v = vt*16+l15][key = kp*32 + quad*8 ..+8]
    const __bf16* v_src = Vtb + (size_t)(nh * 32 + l15) * LQ + kbase + quad * 8;

    // stage chunk 0 into buffer 0
    *(bf16x8*)&Kl[0][(size_t)tid * 8]         = *(const bf16x8*)s_src0;
    *(bf16x8*)&Kl[0][(size_t)(tid + 256) * 8] = *(const bf16x8*)s_src1;
    __syncthreads();

#pragma unroll 2
    for (int ch = 0; ch < 8; ++ch) {
        const int cur = ch & 1;

        // stage next chunk (overlaps this chunk's compute)
        if (ch < 7) {
            *(bf16x8*)&Kl[cur ^ 1][(size_t)tid * 8] =
                *(const bf16x8*)(s_src0 + (size_t)(ch + 1) * 512);
            *(bf16x8*)&Kl[cur ^ 1][(size_t)(tid + 256) * 8] =
                *(const bf16x8*)(s_src1 + (size_t)(ch + 1) * 512);
        }

        // V fragments for THIS chunk (issued early; overlap the S MFMAs)
        bf16x8 vf[2][2];   // [vt][kp]
#pragma unroll
        for (int vt = 0; vt < 2; ++vt)
#pragma unroll
            for (int kp = 0; kp < 2; ++kp)
                vf[vt][kp] = *(const bf16x8*)(v_src + (size_t)vt * 16 * LQ
                                              + ch * 64 + kp * 32);

        // S^T + exp in 2 key-tile pairs (bounds live registers)
#pragma unroll
        for (int ktp = 0; ktp < 2; ++ktp) {
            bf16x8 kf[2][2];
#pragma unroll
            for (int i = 0; i < 2; ++i)
#pragma unroll
                for (int kh = 0; kh < 2; ++kh)
                    kf[i][kh] = *(const bf16x8*)
                        &Kl[cur][(size_t)((ktp * 2 + i) * 128 + kh * 64
                                          + quad * 16 + l15) * 8];

            f4_t s[2][2];
#pragma unroll
            for (int qt = 0; qt < 2; ++qt)
#pragma unroll
                for (int i = 0; i < 2; ++i) {
                    f4_t t = mfma16(kf[i][0], qf[qt][0], fzero);
                    s[qt][i] = mfma16(kf[i][1], qf[qt][1], t);
                }

#pragma unroll
            for (int qt = 0; qt < 2; ++qt)
#pragma unroll
                for (int i = 0; i < 2; ++i) {
                    bf16x4 pv;
                    float d = 0.f;
#pragma unroll
                    for (int r = 0; r < 4; ++r) {
                        float p = __builtin_exp2f(s[qt][i][r]);
                        d += p;
                        pv[r] = (__bf16)p;
                    }
                    den[qt] += d;
                    *(bf16x4*)&P[wave][qt][l15][(ktp * 2 + i) * 16 + quad * 4] = pv;
                }
        }

        // PV: A = V rows, B = P rows (same-wave LDS, in-order DS)
#pragma unroll
        for (int qt = 0; qt < 2; ++qt)
#pragma unroll
            for (int kp = 0; kp < 2; ++kp) {
                bf16x8 pf = *(const bf16x8*)&P[wave][qt][l15][kp * 32 + quad * 8];
                racc[0][qt] = mfma16(vf[0][kp], pf, racc[0][qt]);
                racc[1][qt] = mfma16(vf[1][kp], pf, racc[1][qt]);
            }

        __syncthreads();   // next-buffer K staged; cur free to overwrite
    }

    // den: reduce quad partials (same q = l15 across quads)
#pragma unroll
    for (int qt = 0; qt < 2; ++qt) {
        den[qt] += __shfl_xor(den[qt], 16, 64);
        den[qt] += __shfl_xor(den[qt], 32, 64);
    }

    const size_t pb = (size_t)(nh * KS + ks) * LQ;
    // numPb layout [nh][ks][q][v32] bf16 -- v-contiguous for k3
#pragma unroll
    for (int vt = 0; vt < 2; ++vt)
#pragma unroll
        for (int qt = 0; qt < 2; ++qt) {
            bf16x4 pk;
#pragma unroll
            for (int r = 0; r < 4; ++r) pk[r] = (__bf16)racc[vt][qt][r];
            *(bf16x4*)(numPb + (pb + qbase + qt * 16 + l15) * 32
                             + vt * 16 + quad * 4) = pk;
        }

    if (lane < 16)
#pragma unroll
        for (int qt = 0; qt < 2; ++qt)
            denP[pb + qbase + qt * 16 + lane] = den[qt];
}

// ---------------------------------------------------------------------------
// Kernel 3: vectorized bf16 partial reduce -> R, fp32 projection + residual.
// grid: dim3(256, 2) = l-tile(16) x n = 512 blocks.  block: 256 thr.
// Reduce map: tid = sh(1)|hh(1)|l(4)|vg(2) -> each thread 4x b128 loads,
// per-wave address span contiguous 1 KB per instruction.
// ---------------------------------------------------------------------------
__global__ __launch_bounds__(256) void k3_out(
        const __bf16* __restrict__ numPb, const float* __restrict__ denP,
        const float* __restrict__ Wm, const float* __restrict__ bm,
        const float* __restrict__ x, float* __restrict__ out) {
    const int tid = threadIdx.x;
    const int lt  = blockIdx.x;
    const int n   = blockIdx.y;
    const int l0  = lt * 16;

    __shared__ float Rps[2][64][17];   // [ks-half][j = h*32+v][l]
    __shared__ float dinv[2][16];

    if (tid < 32) {
        const int hh = tid >> 4, li = tid & 15;
        float s = 0.f;
#pragma unroll
        for (int k = 0; k < KS; ++k)
            s += denP[(size_t)((n * 2 + hh) * KS + k) * LQ + l0 + li];
        dinv[hh][li] = 1.0f / s;
    }

    // vectorized reduce over ks (two halves in parallel)
    {
        const int vg = tid & 3, l = (tid >> 2) & 15;
        const int hh = (tid >> 6) & 1, sh = tid >> 7;
        const size_t base = (size_t)(n * 2 + hh) * KS * LQ;
        float a[8] = {0.f, 0.f, 0.f, 0.f, 0.f, 0.f, 0.f, 0.f};
#pragma unroll
        for (int k = 0; k < 4; ++k) {
            const int kk = sh * 4 + k;
            bf16x8 v8 = *(const bf16x8*)(numPb +
                (base + (size_t)kk * LQ + l0 + l) * 32 + vg * 8);
#pragma unroll
            for (int j = 0; j < 8; ++j) a[j] += (float)v8[j];
        }
#pragma unroll
        for (int j = 0; j < 8; ++j)
            Rps[sh][hh * 32 + vg * 8 + j][l] = a[j];
    }
    __syncthreads();

    // projection: thread (l = tid&15, og = tid>>4) -> outputs og*4..+3
    const int l = tid & 15, og = tid >> 4;
    const float d0 = dinv[0][l], d1 = dinv[1][l];
    float rj[64];
#pragma unroll
    for (int j = 0; j < 64; ++j)
        rj[j] = (Rps[0][j][l] + Rps[1][j][l]) * (j < 32 ? d0 : d1);

#pragma unroll
    for (int oi = 0; oi < 4; ++oi) {
        const int o = og * 4 + oi;
        const float* wr = Wm + (size_t)o * 64;
        float a = bm[o];
#pragma unroll
        for (int j4 = 0; j4 < 16; ++j4) {
            f4_t t = *(const f4_t*)(wr + j4 * 4);
            a = fmaf(t[0], rj[j4 * 4 + 0], a);
            a = fmaf(t[1], rj[j4 * 4 + 1], a);
            a = fmaf(t[2], rj[j4 * 4 + 2], a);
            a = fmaf(t[3], rj[j4 * 4 + 3], a);
        }
        const size_t idx = (size_t)(n * 64 + o) * LQ + l0 + l;
        out[idx] = a + x[idx];
    }
}

// ---------------------------------------------------------------------------
extern "C" void kernel_launch(void* const* d_in, const int* in_sizes, int n_in,
                              void* d_out, int out_size, void* d_ws, size_t ws_size,
                              hipStream_t stream) {
    const float* x  = (const float*)d_in[0];
    const float* Wq = (const float*)d_in[1];
    const float* bq = (const float*)d_in[2];
    const float* Wk = (const float*)d_in[3];
    const float* bk = (const float*)d_in[4];
    const float* Wv = (const float*)d_in[5];
    const float* bv = (const float*)d_in[6];
    const float* Wm = (const float*)d_in[7];
    const float* bm = (const float*)d_in[8];
    float* out = (float*)d_out;

    // workspace carve: Qb 2MB | Kb 2MB | Vtb 1MB | numPb 8.4MB | denP 0.5MB
    __bf16* Qb    = (__bf16*)d_ws;
    __bf16* Kb    = Qb + (size_t)NH * LQ * 64;
    __bf16* Vtb   = Kb + (size_t)NH * LQ * 64;
    __bf16* numPb = Vtb + (size_t)NH * 32 * LQ;
    float*  denP  = (float*)(numPb + (size_t)NH * KS * LQ * 32);

    k1_qkv<<<dim3(128, 2), dim3(256), 0, stream>>>(x, Wq, bq, Wk, bk, Wv, bv,
                                                   Qb, Kb, Vtb);
    k2_attn<<<dim3(32, NH, KS), dim3(256), 0, stream>>>(Qb, Kb, Vtb, numPb, denP);
    k3_out<<<dim3(256, 2), dim3(256), 0, stream>>>(numPb, denP, Wm, bm, x, out);
}